// Round 1
// baseline (48.293 us; speedup 1.0000x reference)
//
#include <hip/hip_runtime.h>

#define CHUNK 512   // gts/preds points staged per block (8 KB LDS as float4)

// ---- order-preserving float <-> uint encoding (for atomicMin on floats) ----
__device__ __forceinline__ unsigned enc_f(float f) {
    unsigned u = __float_as_uint(f);
    return (u & 0x80000000u) ? ~u : (u | 0x80000000u);
}
__device__ __forceinline__ float dec_f(unsigned e) {
    unsigned u = (e & 0x80000000u) ? (e ^ 0x80000000u) : ~e;
    return __uint_as_float(u);
}

__global__ __launch_bounds__(256) void init_kernel(unsigned* __restrict__ mins, int n,
                                                   float* __restrict__ out) {
    int i = blockIdx.x * 256 + threadIdx.x;
    if (i < n) mins[i] = 0xFFFFFFFFu;   // encodes "+infinity" for the uint min
    if (i == 0) out[0] = 0.0f;
}

// For each query point q (one thread each), min over a CHUNK of "points":
//   val = ry_q + min_k ( rx_k - 2 * dot(pt_k, q) )
// pts: [B, NP, 3], qrs: [B, NQ, 3], mins: [B, NQ] encoded uint
__global__ __launch_bounds__(256) void min_kernel(const float* __restrict__ pts,
                                                  const float* __restrict__ qrs,
                                                  unsigned* __restrict__ mins,
                                                  int NP, int NQ) {
    const int b  = blockIdx.z;
    const int j  = blockIdx.x * 256 + threadIdx.x;
    const int i0 = blockIdx.y * CHUNK;

    __shared__ float4 s[CHUNK];
    const float* pb = pts + (size_t)b * NP * 3;
    for (int idx = threadIdx.x; idx < CHUNK; idx += 256) {
        float x = pb[(size_t)(i0 + idx) * 3 + 0];
        float y = pb[(size_t)(i0 + idx) * 3 + 1];
        float z = pb[(size_t)(i0 + idx) * 3 + 2];
        s[idx] = make_float4(x, y, z, x * x + y * y + z * z);
    }
    __syncthreads();

    const float* q = qrs + ((size_t)b * NQ + j) * 3;
    const float px = q[0], py = q[1], pz = q[2];
    const float ry = px * px + py * py + pz * pz;
    const float ax = -2.0f * px, ay = -2.0f * py, az = -2.0f * pz;

    float mm0 = 3.4e38f, mm1 = 3.4e38f, mm2 = 3.4e38f, mm3 = 3.4e38f;
    for (int k = 0; k < CHUNK; k += 4) {
        float4 p0 = s[k + 0];
        float4 p1 = s[k + 1];
        float4 p2 = s[k + 2];
        float4 p3 = s[k + 3];
        float t0 = fmaf(p0.x, ax, fmaf(p0.y, ay, fmaf(p0.z, az, p0.w)));
        float t1 = fmaf(p1.x, ax, fmaf(p1.y, ay, fmaf(p1.z, az, p1.w)));
        float t2 = fmaf(p2.x, ax, fmaf(p2.y, ay, fmaf(p2.z, az, p2.w)));
        float t3 = fmaf(p3.x, ax, fmaf(p3.y, ay, fmaf(p3.z, az, p3.w)));
        mm0 = fminf(mm0, t0);
        mm1 = fminf(mm1, t1);
        mm2 = fminf(mm2, t2);
        mm3 = fminf(mm3, t3);
    }
    float m   = fminf(fminf(mm0, mm1), fminf(mm2, mm3));
    float val = ry + m;
    atomicMin(&mins[(size_t)b * NQ + j], enc_f(val));
}

__global__ __launch_bounds__(256) void huber_kernel(const unsigned* __restrict__ mins, int n,
                                                    const float* __restrict__ cp,
                                                    float* __restrict__ partials) {
    const float c = cp[0];
    float acc = 0.0f;
    for (int i = blockIdx.x * 256 + threadIdx.x; i < n; i += gridDim.x * 256) {
        float x = dec_f(mins[i]);
        acc += (x < c) ? (0.5f * x * x) : fmaf(c, x, -0.5f * c * c);
    }
    // wave64 reduce
    for (int off = 32; off > 0; off >>= 1) acc += __shfl_down(acc, off, 64);
    __shared__ float ls[4];
    int lane = threadIdx.x & 63, w = threadIdx.x >> 6;
    if (lane == 0) ls[w] = acc;
    __syncthreads();
    if (threadIdx.x == 0) partials[blockIdx.x] = ls[0] + ls[1] + ls[2] + ls[3];
}

__global__ __launch_bounds__(64) void final_kernel(const float* __restrict__ partials, int n,
                                                   float* __restrict__ out) {
    float acc = 0.0f;
    for (int i = threadIdx.x; i < n; i += 64) acc += partials[i];
    for (int off = 32; off > 0; off >>= 1) acc += __shfl_down(acc, off, 64);
    if (threadIdx.x == 0) out[0] = acc;
}

extern "C" void kernel_launch(void* const* d_in, const int* in_sizes, int n_in,
                              void* d_out, int out_size, void* d_ws, size_t ws_size,
                              hipStream_t stream) {
    const float* preds = (const float*)d_in[0];  // [B, M, 3]
    const float* gts   = (const float*)d_in[1];  // [B, N, 3]
    const float* cp    = (const float*)d_in[2];  // [1]
    float* out = (float*)d_out;

    const int B = 8, N = 4096, M = 4096;

    unsigned* mins1   = (unsigned*)d_ws;           // [B*M]  min over gts, per pred
    unsigned* mins2   = mins1 + (size_t)B * M;     // [B*N]  min over preds, per gt
    float*    partials = (float*)(mins2 + (size_t)B * N);

    const int totalMins = B * (M + N);

    init_kernel<<<(totalMins + 255) / 256, 256, 0, stream>>>(mins1, totalMins, out);

    // pass 1: for each pred j, min over gts  -> mins1
    dim3 g1(M / 256, N / CHUNK, B);
    min_kernel<<<g1, 256, 0, stream>>>(gts, preds, mins1, N, M);

    // pass 2: for each gt i, min over preds  -> mins2
    dim3 g2(N / 256, M / CHUNK, B);
    min_kernel<<<g2, 256, 0, stream>>>(preds, gts, mins2, M, N);

    const int NBLK = 64;
    huber_kernel<<<NBLK, 256, 0, stream>>>(mins1, totalMins, cp, partials);
    final_kernel<<<1, 64, 0, stream>>>(partials, NBLK, out);
}

// Round 2
// 32.986 us; speedup vs baseline: 1.4641x; 1.4641x over previous
//
#include <hip/hip_runtime.h>

typedef float v2f __attribute__((ext_vector_type(2)));
typedef float v4f __attribute__((ext_vector_type(4)));

#define NPTS   4096
#define CHUNK  256                 // points staged per block
#define G4     (CHUNK / 4)         // 64 groups of 4 points
#define QPT    4                   // queries per thread
#define TPB    256
#define QPB    (TPB * QPT)         // 1024 queries per block
#define NCHUNK (NPTS / CHUNK)      // 16
#define NZ     16                  // B * 2 passes

__device__ __forceinline__ v2f pk_fma(v2f a, v2f b, v2f c) {
    v2f d;
    asm("v_pk_fma_f32 %0, %1, %2, %3" : "=v"(d) : "v"(a), "v"(b), "v"(c));
    return d;
}
__device__ __forceinline__ float min3f(float a, float b, float c) {
    float d;
    asm("v_min3_f32 %0, %1, %2, %3" : "=v"(d) : "v"(a), "v"(b), "v"(c));
    return d;
}

// One dispatch covers BOTH chamfer directions (blockIdx.z = b*2 + pass).
// Each block: stage CHUNK points (SoA 4-point groups, w = |p|^2 folded in),
// each thread computes min over the chunk for QPT queries, writes partial min.
__global__ __launch_bounds__(TPB, 4) void min_kernel(const float* __restrict__ preds,
                                                     const float* __restrict__ gts,
                                                     float* __restrict__ partial) {
    const int z    = blockIdx.z;          // b*2 + pass
    const int b    = z >> 1;
    const int pass = z & 1;
    const float* pts = pass ? preds : gts;   // pass0: min over gts (per pred)
    const float* qrs = pass ? gts   : preds; // pass1: min over preds (per gt)

    const int chunk = blockIdx.y;
    const int i0    = chunk * CHUNK;
    const int tid   = threadIdx.x;

    __shared__ v4f SX[G4], SY[G4], SZ[G4], SW[G4];

    // ---- stage CHUNK points, transposed to 4-point SoA groups ----
    {
        const float* pb = pts + ((size_t)b * NPTS + i0) * 3;
        float x  = pb[tid * 3 + 0];
        float y  = pb[tid * 3 + 1];
        float zz = pb[tid * 3 + 2];
        float w  = fmaf(x, x, fmaf(y, y, zz * zz));
        ((float*)SX)[tid] = x;
        ((float*)SY)[tid] = y;
        ((float*)SZ)[tid] = zz;
        ((float*)SW)[tid] = w;
    }

    // ---- load QPT queries, precompute -2q broadcast pairs ----
    const float* qb    = qrs + (size_t)b * NPTS * 3;
    const int    jbase = blockIdx.x * QPB + tid;
    v2f   AX[QPT], AY[QPT], AZ[QPT];
    float R[QPT], acc[QPT];
#pragma unroll
    for (int q = 0; q < QPT; ++q) {
        int   j  = jbase + q * TPB;
        float qx = qb[j * 3 + 0];
        float qy = qb[j * 3 + 1];
        float qz = qb[j * 3 + 2];
        R[q]   = fmaf(qx, qx, fmaf(qy, qy, qz * qz));
        float ax = -2.0f * qx, ay = -2.0f * qy, az = -2.0f * qz;
        AX[q] = (v2f){ax, ax};
        AY[q] = (v2f){ay, ay};
        AZ[q] = (v2f){az, az};
        acc[q] = 3.4e38f;
    }
    __syncthreads();

    // ---- main loop: 4 points x QPT queries per group ----
#pragma unroll 4
    for (int g = 0; g < G4; ++g) {
        v4f X = SX[g], Y = SY[g], Z = SZ[g], W = SW[g];
        v2f xlo = X.lo, xhi = X.hi;
        v2f ylo = Y.lo, yhi = Y.hi;
        v2f zlo = Z.lo, zhi = Z.hi;
        v2f wlo = W.lo, whi = W.hi;
#pragma unroll
        for (int q = 0; q < QPT; ++q) {
            v2f t0 = pk_fma(xlo, AX[q], pk_fma(ylo, AY[q], pk_fma(zlo, AZ[q], wlo)));
            v2f t1 = pk_fma(xhi, AX[q], pk_fma(yhi, AY[q], pk_fma(zhi, AZ[q], whi)));
            acc[q] = min3f(t0.x, t0.y, min3f(t1.x, t1.y, acc[q]));
        }
    }

    // ---- write partial mins (one slot per (z, chunk, query): no atomics) ----
    float* dst = partial + ((size_t)z * NCHUNK + chunk) * NPTS;
#pragma unroll
    for (int q = 0; q < QPT; ++q) {
        dst[jbase + q * TPB] = R[q] + acc[q];
    }
}

// min over the NCHUNK partials per query, huber, block-sum.
__global__ __launch_bounds__(256) void huber_kernel(const float* __restrict__ partial,
                                                    const float* __restrict__ cp,
                                                    float* __restrict__ bp) {
    const int s = blockIdx.x * 256 + threadIdx.x;   // [0, NZ*NPTS)
    const int z = s >> 12, j = s & (NPTS - 1);
    const float* p = partial + (size_t)z * NCHUNK * NPTS + j;
    float m = 3.4e38f;
#pragma unroll
    for (int c = 0; c < NCHUNK; ++c) m = fminf(m, p[(size_t)c * NPTS]);
    const float cc = cp[0];
    float h = (m < cc) ? (0.5f * m * m) : fmaf(cc, m, -0.5f * cc * cc);
    for (int off = 32; off > 0; off >>= 1) h += __shfl_down(h, off, 64);
    __shared__ float ls[4];
    if ((threadIdx.x & 63) == 0) ls[threadIdx.x >> 6] = h;
    __syncthreads();
    if (threadIdx.x == 0) bp[blockIdx.x] = ls[0] + ls[1] + ls[2] + ls[3];
}

__global__ __launch_bounds__(256) void final_kernel(const float* __restrict__ bp,
                                                    float* __restrict__ out) {
    float a = bp[threadIdx.x];   // exactly 256 block partials
    for (int off = 32; off > 0; off >>= 1) a += __shfl_down(a, off, 64);
    __shared__ float ls[4];
    if ((threadIdx.x & 63) == 0) ls[threadIdx.x >> 6] = a;
    __syncthreads();
    if (threadIdx.x == 0) out[0] = ls[0] + ls[1] + ls[2] + ls[3];
}

extern "C" void kernel_launch(void* const* d_in, const int* in_sizes, int n_in,
                              void* d_out, int out_size, void* d_ws, size_t ws_size,
                              hipStream_t stream) {
    const float* preds = (const float*)d_in[0];  // [8, 4096, 3]
    const float* gts   = (const float*)d_in[1];  // [8, 4096, 3]
    const float* cp    = (const float*)d_in[2];  // [1]
    float* out = (float*)d_out;

    float* partial = (float*)d_ws;                            // [NZ][NCHUNK][NPTS] = 4 MB
    float* bp      = partial + (size_t)NZ * NCHUNK * NPTS;    // [256]

    dim3 gm(NPTS / QPB, NCHUNK, NZ);   // (4, 16, 16) = 1024 blocks
    min_kernel<<<gm, TPB, 0, stream>>>(preds, gts, partial);

    huber_kernel<<<(NZ * NPTS) / 256, 256, 0, stream>>>(partial, cp, bp);
    final_kernel<<<1, 256, 0, stream>>>(bp, out);
}